// Round 2
// baseline (1622.596 us; speedup 1.0000x reference)
//
#include <hip/hip_runtime.h>
#include <cstdint>
#include <cstddef>

#define B_     16
#define T_     128
#define J_     24
#define H_     256
#define HEADS_ 8
#define DH_    32
#define L_     4
#define RANK_  8
#define M_     12
#define NTOK   (B_*T_)       // 2048
#define ROWS   (NTOK*J_)     // 49152
#define HAS_G_MASK 3821      // bit m set iff NUM_GLOBAL_LIST[m] > 0

typedef __attribute__((ext_vector_type(8))) short short8;
typedef __attribute__((ext_vector_type(4))) float f32x4;

__constant__ int cNJ[M_] = {8, 10, 12, 14, 16, 18, 20, 22, 24, 9, 13, 17};

__device__ __forceinline__ float bf2f(unsigned short u) {
    union { unsigned int i; float f; } c; c.i = ((unsigned int)u) << 16; return c.f;
}
__device__ __forceinline__ unsigned short f2bf(float f) {
    union { float f; unsigned int i; } c; c.f = f;
    unsigned int x = c.i;
    return (unsigned short)((x + 0x7fffu + ((x >> 16) & 1u)) >> 16);
}
__device__ __forceinline__ void gload16(const void* g, void* l) {
    __builtin_amdgcn_global_load_lds((const __attribute__((address_space(1))) void*)g,
                                     (__attribute__((address_space(3))) void*)l, 16, 0, 0);
}

// ---------------------------------------------------------------- mask dtype probe
__global__ void zero_flag(int* f) { *f = 0; }

// If masks are stored as 1-byte bools, slide+hinge+global == valid for EVERY
// element. If stored as int32 (or f32), the byte view violates this massively.
__global__ __launch_bounds__(256) void detect_kernel(
    const unsigned char* __restrict__ sl, const unsigned char* __restrict__ hi,
    const unsigned char* __restrict__ gl, const int* __restrict__ m_idx,
    int* __restrict__ flag) {
    int rj = blockIdx.x * 256 + threadIdx.x;
    if (rj >= ROWS) return;
    int b = rj / (T_ * J_);
    int j = rj % J_;
    int valid = (j < cNJ[m_idx[b]]) ? 1 : 0;
    int cnt = (sl[rj] != 0) + (hi[rj] != 0) + (gl[rj] != 0);
    if (cnt != valid) atomicOr(flag, 1);
}

// ---------------------------------------------------------------- weights f32 -> bf16 transposed
// src: [L][K][Nc] f32  ->  dst: [L][Nc][K] bf16
__global__ void wconv_t(const float* __restrict__ W, unsigned short* __restrict__ WT,
                        int K, int Nc, int total) {
    int i = blockIdx.x * 256 + threadIdx.x;
    if (i >= total) return;
    int kn = K * Nc;
    int l = i / kn;
    int r = i - l * kn;
    int k = r / Nc;
    int n = r - k * Nc;
    WT[(size_t)l * kn + (size_t)n * K + k] = f2bf(W[i]);
}

// ---------------------------------------------------------------- embedding (wave per row)
__global__ __launch_bounds__(256) void embed_kernel(
    const float* __restrict__ act, const void* __restrict__ slide,
    const void* __restrict__ hinge, const void* __restrict__ glob,
    const int* __restrict__ m_idx, const int* __restrict__ flag,
    const float* __restrict__ Ws, const float* __restrict__ bs,
    const float* __restrict__ Wh, const float* __restrict__ bh,
    const float* __restrict__ Wg, const float* __restrict__ Wact,
    const float* __restrict__ pos, float* __restrict__ X) {
    int rj = (blockIdx.x << 2) + (threadIdx.x >> 6);
    int lane = threadIdx.x & 63;
    int b = rj / (T_ * J_);
    int j = rj % J_;
    int m = m_idx[b];
    bool valid = j < cNJ[m];
    bool s, hh, gl;
    if (*flag) {
        s  = ((const int*)slide)[rj] != 0;
        hh = ((const int*)hinge)[rj] != 0;
        gl = ((const int*)glob)[rj]  != 0;
    } else {
        s  = ((const unsigned char*)slide)[rj] != 0;
        hh = ((const unsigned char*)hinge)[rj] != 0;
        gl = ((const unsigned char*)glob)[rj]  != 0;
    }
    float a1 = act[rj];
    int h0 = lane << 2;
    float e0 = 0.f, e1 = 0.f, e2 = 0.f, e3 = 0.f;
    if (s) {
        float4 w = *(const float4*)(Ws + h0); float4 bb = *(const float4*)(bs + h0);
        e0 = a1 * w.x + bb.x; e1 = a1 * w.y + bb.y; e2 = a1 * w.z + bb.z; e3 = a1 * w.w + bb.w;
    } else if (hh) {
        float4 w = *(const float4*)(Wh + h0); float4 bb = *(const float4*)(bh + h0);
        e0 = a1 * w.x + bb.x; e1 = a1 * w.y + bb.y; e2 = a1 * w.z + bb.z; e3 = a1 * w.w + bb.w;
    } else if (gl && ((HAS_G_MASK >> m) & 1)) {
        float4 w = *(const float4*)(Wg + m * H_ + h0);
        e0 = a1 * w.x; e1 = a1 * w.y; e2 = a1 * w.z; e3 = a1 * w.w;
    }
    if (valid) {
        float4 wa = *(const float4*)(Wact + h0);
        e0 += wa.x; e1 += wa.y; e2 += wa.z; e3 += wa.w;
    }
    float4 pv = *(const float4*)(pos + (size_t)(m * J_ + j) * H_ + h0);
    float4 out; out.x = e0 + pv.x; out.y = e1 + pv.y; out.z = e2 + pv.z; out.w = e3 + pv.w;
    *(float4*)(X + ((size_t)rj << 8) + h0) = out;
}

// ---------------------------------------------------------------- LayerNorm (+ optional LoRA-A), wave per row
template<bool LORA>
__global__ __launch_bounds__(256) void ln_kernel(
    const float* __restrict__ X, const float* __restrict__ sc, const float* __restrict__ bi,
    const float* __restrict__ lA, const int* __restrict__ m_idx,
    unsigned short* __restrict__ Hbf, float* __restrict__ Rbuf) {
    int row = (blockIdx.x << 2) + (threadIdx.x >> 6);
    int lane = threadIdx.x & 63;
    int h0 = lane << 2;
    float4 xv = *(const float4*)(X + ((size_t)row << 8) + h0);
    float s1 = xv.x + xv.y + xv.z + xv.w;
    float s2 = xv.x * xv.x + xv.y * xv.y + xv.z * xv.z + xv.w * xv.w;
    #pragma unroll
    for (int o = 32; o; o >>= 1) { s1 += __shfl_xor(s1, o); s2 += __shfl_xor(s2, o); }
    float mu = s1 * (1.f / H_);
    float var = s2 * (1.f / H_) - mu * mu;
    float rs = rsqrtf(var + 1e-5f);
    float4 scv = *(const float4*)(sc + h0);
    float4 biv = *(const float4*)(bi + h0);
    float hn0 = (xv.x - mu) * rs * scv.x + biv.x;
    float hn1 = (xv.y - mu) * rs * scv.y + biv.y;
    float hn2 = (xv.z - mu) * rs * scv.z + biv.z;
    float hn3 = (xv.w - mu) * rs * scv.w + biv.w;
    ushort4 o4; o4.x = f2bf(hn0); o4.y = f2bf(hn1); o4.z = f2bf(hn2); o4.w = f2bf(hn3);
    *(ushort4*)(Hbf + ((size_t)row << 8) + h0) = o4;
    if (LORA) {
        int t = m_idx[row / (J_ * T_)];
        const float* Ap = lA + (size_t)t * (H_ * RANK_) + h0 * RANK_;  // 32 consecutive floats
        float4 av[8];
        #pragma unroll
        for (int c = 0; c < 8; ++c) av[c] = ((const float4*)Ap)[c];
        float hn[4] = {hn0, hn1, hn2, hn3};
        float p[RANK_];
        #pragma unroll
        for (int k = 0; k < RANK_; ++k) p[k] = 0.f;
        #pragma unroll
        for (int i = 0; i < 4; ++i)
            #pragma unroll
            for (int k = 0; k < RANK_; ++k) {
                int idx = i * RANK_ + k;
                float a = (idx & 3) == 0 ? av[idx >> 2].x : (idx & 3) == 1 ? av[idx >> 2].y
                        : (idx & 3) == 2 ? av[idx >> 2].z : av[idx >> 2].w;
                p[k] += hn[i] * a;
            }
        #pragma unroll
        for (int k = 0; k < RANK_; ++k)
            #pragma unroll
            for (int o = 32; o; o >>= 1) p[k] += __shfl_xor(p[k], o);
        if (lane == 0) {
            #pragma unroll
            for (int k = 0; k < RANK_; ++k) Rbuf[(size_t)row * RANK_ + k] = p[k];
        }
    }
}

// ---------------------------------------------------------------- final LayerNorm (in place, wave per row)
__global__ __launch_bounds__(256) void lnf_kernel(
    float* __restrict__ X, const float* __restrict__ sc, const float* __restrict__ bi) {
    int row = (blockIdx.x << 2) + (threadIdx.x >> 6);
    int lane = threadIdx.x & 63;
    int h0 = lane << 2;
    float4 xv = *(const float4*)(X + ((size_t)row << 8) + h0);
    float s1 = xv.x + xv.y + xv.z + xv.w;
    float s2 = xv.x * xv.x + xv.y * xv.y + xv.z * xv.z + xv.w * xv.w;
    #pragma unroll
    for (int o = 32; o; o >>= 1) { s1 += __shfl_xor(s1, o); s2 += __shfl_xor(s2, o); }
    float mu = s1 * (1.f / H_);
    float var = s2 * (1.f / H_) - mu * mu;
    float rs = rsqrtf(var + 1e-5f);
    float4 scv = *(const float4*)(sc + h0);
    float4 biv = *(const float4*)(bi + h0);
    float4 out;
    out.x = (xv.x - mu) * rs * scv.x + biv.x;
    out.y = (xv.y - mu) * rs * scv.y + biv.y;
    out.z = (xv.z - mu) * rs * scv.z + biv.z;
    out.w = (xv.w - mu) * rs * scv.w + biv.w;
    *(float4*)(X + ((size_t)row << 8) + h0) = out;
}

// ---------------------------------------------------------------- GEMM: C = A[ROWSxK] @ B[KxNc] (+epilogue)
// A bf16 row-major (lda=K). BT bf16 = B transposed, (Nc x K) row-major (lda=K).
// EPI: 0 = QKV (bias + LoRA-B, store bf16, ld 768)
//      1 = GELU (bias + gelu, store bf16, ld Nc)
//      2 = RESID (bias, X += g*val, ld 256)
template<int EPI>
__global__ __launch_bounds__(256) void gemm_k(
    const unsigned short* __restrict__ A, const unsigned short* __restrict__ BT,
    const float* __restrict__ bias,
    const float* __restrict__ aux1,   // QKV: Rbuf   RESID: gvec
    const float* __restrict__ aux2,   // QKV: loraB_l [M][RANK][768]
    const int* __restrict__ m_idx,
    unsigned short* __restrict__ outB, float* __restrict__ outF,
    int K, int Nc) {
    __shared__ __align__(16) unsigned short As[128 * 64];
    __shared__ __align__(16) unsigned short Bs[128 * 64];
    // XCD-aware bijective swizzle (all our grids have nwg % 8 == 0)
    int gx = gridDim.x;
    int nwg = gx * gridDim.y;
    int id = blockIdx.y * gx + blockIdx.x;
    int bx = blockIdx.x, by = blockIdx.y;
    if ((nwg & 7) == 0) {
        int q8 = nwg >> 3;
        int sid = (id & 7) * q8 + (id >> 3);
        bx = sid % gx; by = sid / gx;
    }
    int col0 = bx * 128;
    int row0 = by * 128;
    int tid = threadIdx.x;
    int wv = tid >> 6, lane = tid & 63;
    int wm = wv >> 1, wn = wv & 1;

    f32x4 acc[4][4];
    const f32x4 z = {0.f, 0.f, 0.f, 0.f};
    #pragma unroll
    for (int mi = 0; mi < 4; ++mi)
        #pragma unroll
        for (int ni = 0; ni < 4; ++ni) acc[mi][ni] = z;

    for (int k0 = 0; k0 < K; k0 += 64) {
        #pragma unroll
        for (int it = 0; it < 4; ++it) {
            int f = (tid << 4) + (it << 12);       // byte offset in 16KB tile
            int r = f >> 7;                        // tile row (128 B per row)
            int ce = (f & 127) >> 1;               // element within row
            gload16(A  + (size_t)(row0 + r) * K + k0 + ce, (char*)As + f);
            gload16(BT + (size_t)(col0 + r) * K + k0 + ce, (char*)Bs + f);
        }
        __syncthreads();
        #pragma unroll
        for (int kk = 0; kk < 64; kk += 32) {
            short8 af[4], bfr[4];
            int ko = kk + ((lane >> 4) << 3);
            #pragma unroll
            for (int q = 0; q < 4; ++q) {
                af[q]  = *(const short8*)(As + ((wm * 64 + q * 16 + (lane & 15)) << 6) + ko);
                bfr[q] = *(const short8*)(Bs + ((wn * 64 + q * 16 + (lane & 15)) << 6) + ko);
            }
            #pragma unroll
            for (int mi = 0; mi < 4; ++mi)
                #pragma unroll
                for (int ni = 0; ni < 4; ++ni)
                    acc[mi][ni] = __builtin_amdgcn_mfma_f32_16x16x32_bf16(af[mi], bfr[ni], acc[mi][ni], 0, 0, 0);
        }
        __syncthreads();
    }

    int rbase = row0 + wm * 64 + ((lane >> 4) << 2);
    int cbase = col0 + wn * 64 + (lane & 15);

    if (EPI == 0) {
        int t = m_idx[row0 / (J_ * T_)];           // block-uniform: 3072 % 128 == 0
        const float* lB = aux2 + (size_t)t * (RANK_ * 3 * H_);
        float lbv[4][RANK_];
        #pragma unroll
        for (int ni = 0; ni < 4; ++ni)
            #pragma unroll
            for (int kq = 0; kq < RANK_; ++kq)
                lbv[ni][kq] = lB[kq * (3 * H_) + cbase + ni * 16];
        #pragma unroll
        for (int mi = 0; mi < 4; ++mi) {
            #pragma unroll
            for (int r = 0; r < 4; ++r) {
                int row = rbase + mi * 16 + r;
                const float* Rr = aux1 + (size_t)row * RANK_;
                float rv[RANK_];
                #pragma unroll
                for (int kq = 0; kq < RANK_; ++kq) rv[kq] = Rr[kq];
                #pragma unroll
                for (int ni = 0; ni < 4; ++ni) {
                    int col = cbase + ni * 16;
                    float val = acc[mi][ni][r] + bias[col];
                    #pragma unroll
                    for (int kq = 0; kq < RANK_; ++kq) val += rv[kq] * lbv[ni][kq];
                    outB[(size_t)row * (3 * H_) + col] = f2bf(val);
                }
            }
        }
    } else if (EPI == 1) {
        #pragma unroll
        for (int mi = 0; mi < 4; ++mi)
            #pragma unroll
            for (int r = 0; r < 4; ++r) {
                int row = rbase + mi * 16 + r;
                #pragma unroll
                for (int ni = 0; ni < 4; ++ni) {
                    int col = cbase + ni * 16;
                    float u = acc[mi][ni][r] + bias[col];
                    float zz = 0.7978845608028654f * (u + 0.044715f * u * u * u);
                    float tt = __expf(-2.f * fabsf(zz));
                    float th = (1.f - tt) / (1.f + tt);
                    th = zz < 0.f ? -th : th;
                    outB[(size_t)row * Nc + col] = f2bf(0.5f * u * (1.f + th));
                }
            }
    } else {
        #pragma unroll
        for (int mi = 0; mi < 4; ++mi)
            #pragma unroll
            for (int r = 0; r < 4; ++r) {
                int row = rbase + mi * 16 + r;
                #pragma unroll
                for (int ni = 0; ni < 4; ++ni) {
                    int col = cbase + ni * 16;
                    float u = acc[mi][ni][r] + bias[col];
                    outF[(size_t)row * H_ + col] += aux1[col] * u;
                }
            }
    }
}

// ---------------------------------------------------------------- attention: one wave per (token, head)
__global__ __launch_bounds__(64) void attn_kernel(
    const unsigned short* __restrict__ QKV, const int* __restrict__ m_idx,
    unsigned short* __restrict__ O) {
    int blk = blockIdx.x;
    int n = blk >> 3;
    int hd = blk & 7;
    int b = n >> 7;
    int lane = threadIdx.x;
    int nj = cNJ[m_idx[b]];
    __shared__ float q[J_][DH_], k[J_][DH_], v[J_][DH_], sc[J_][J_];

    const unsigned short* base = QKV + (size_t)n * J_ * (3 * H_) + hd * DH_;
    #pragma unroll
    for (int it = 0; it < 3; ++it) {
        int idx = it * 256 + (lane << 2);        // 768 = J*DH
        int j = idx >> 5, d = idx & 31;
        const unsigned short* p = base + j * (3 * H_) + d;
        ushort4 qv = *(const ushort4*)(p);
        ushort4 kv = *(const ushort4*)(p + H_);
        ushort4 vv = *(const ushort4*)(p + 2 * H_);
        q[j][d] = bf2f(qv.x); q[j][d+1] = bf2f(qv.y); q[j][d+2] = bf2f(qv.z); q[j][d+3] = bf2f(qv.w);
        k[j][d] = bf2f(kv.x); k[j][d+1] = bf2f(kv.y); k[j][d+2] = bf2f(kv.z); k[j][d+3] = bf2f(kv.w);
        v[j][d] = bf2f(vv.x); v[j][d+1] = bf2f(vv.y); v[j][d+2] = bf2f(vv.z); v[j][d+3] = bf2f(vv.w);
    }
    __syncthreads();

    const float scale = 0.17677669529663687f;   // 1/sqrt(32)
    #pragma unroll
    for (int it = 0; it < 9; ++it) {
        int idx = it * 64 + lane;            // 576 = J*J
        int i = idx / J_, j = idx - i * J_;
        float s = 0.f;
        #pragma unroll
        for (int d = 0; d < DH_; ++d) s += q[i][d] * k[j][d];
        bool ok = (i < nj && j < nj) || (i == j);
        sc[i][j] = ok ? s * scale : -3.4028234663852886e38f;
    }
    __syncthreads();

    if (lane < J_) {
        float mx = -3.4028234663852886e38f;
        #pragma unroll
        for (int j = 0; j < J_; ++j) mx = fmaxf(mx, sc[lane][j]);
        float sm = 0.f;
        #pragma unroll
        for (int j = 0; j < J_; ++j) { float e = __expf(sc[lane][j] - mx); sc[lane][j] = e; sm += e; }
        float inv = 1.f / sm;
        #pragma unroll
        for (int j = 0; j < J_; ++j) sc[lane][j] *= inv;
    }
    __syncthreads();

    #pragma unroll
    for (int it = 0; it < 6; ++it) {
        int idx = it * 128 + (lane << 1);
        int i = idx >> 5, d = idx & 31;
        float o0 = 0.f, o1 = 0.f;
        #pragma unroll
        for (int j = 0; j < J_; ++j) {
            float a = sc[i][j];
            o0 += a * v[j][d];
            o1 += a * v[j][d + 1];
        }
        ushort2 st; st.x = f2bf(o0); st.y = f2bf(o1);
        *(ushort2*)(O + (size_t)(n * J_ + i) * H_ + hd * DH_ + d) = st;
    }
}

// ---------------------------------------------------------------- host
extern "C" void kernel_launch(void* const* d_in, const int* in_sizes, int n_in,
                              void* d_out, int out_size, void* d_ws, size_t ws_size,
                              hipStream_t stream) {
    (void)in_sizes; (void)n_in; (void)out_size; (void)ws_size;
    const float* act   = (const float*)d_in[0];
    const void*  slide = d_in[1];
    const void*  hinge = d_in[2];
    const void*  glob  = d_in[3];
    // d_in[4] = act_mask  (recomputed from m_idx), d_in[5] = morph_mask (recomputed)
    const int* m_idx  = (const int*)d_in[6];
    const float* Ws   = (const float*)d_in[7];
    const float* bs   = (const float*)d_in[8];
    const float* Wh   = (const float*)d_in[9];
    const float* bh   = (const float*)d_in[10];
    const float* Wg   = (const float*)d_in[11];
    const float* Wact = (const float*)d_in[12];
    const float* pos  = (const float*)d_in[13];
    const float* ln1s = (const float*)d_in[14];
    const float* ln1b = (const float*)d_in[15];
    const float* Wqkv = (const float*)d_in[16];
    const float* bqkv = (const float*)d_in[17];
    const float* loraA= (const float*)d_in[18];
    const float* loraB= (const float*)d_in[19];
    const float* Wo   = (const float*)d_in[20];
    const float* bo   = (const float*)d_in[21];
    const float* ln2s = (const float*)d_in[22];
    const float* ln2b = (const float*)d_in[23];
    const float* W1   = (const float*)d_in[24];
    const float* b1   = (const float*)d_in[25];
    const float* W2   = (const float*)d_in[26];
    const float* b2   = (const float*)d_in[27];
    const float* g1   = (const float*)d_in[28];
    const float* g2   = (const float*)d_in[29];
    const float* lnfs = (const float*)d_in[30];
    const float* lnfb = (const float*)d_in[31];

    float* X = (float*)d_out;   // residual stream lives in d_out (same shape/size)

    size_t off = 0;
    char* ws = (char*)d_ws;
    auto nxt = [&](size_t bytes) -> char* {
        char* p = ws + off; off += (bytes + 255) & ~(size_t)255; return p;
    };
    int*            dflag = (int*)nxt(256);
    unsigned short* Hbf   = (unsigned short*)nxt((size_t)ROWS * H_ * 2);        // 25 MB (also Obf)
    unsigned short* QKVG  = (unsigned short*)nxt((size_t)ROWS * 1024 * 2);      // 101 MB (QKV & gelu alias)
    float*          Rbuf  = (float*)nxt((size_t)ROWS * RANK_ * 4);              // 1.6 MB
    unsigned short* WqkvT = (unsigned short*)nxt((size_t)L_ * H_ * 768 * 2);
    unsigned short* WoT   = (unsigned short*)nxt((size_t)L_ * H_ * H_ * 2);
    unsigned short* W1T   = (unsigned short*)nxt((size_t)L_ * H_ * 1024 * 2);
    unsigned short* W2T   = (unsigned short*)nxt((size_t)L_ * 1024 * H_ * 2);
    unsigned short* Obf   = Hbf;   // lifetimes disjoint: attn writes after QKV-GEMM consumed Hbf

    zero_flag<<<1, 1, 0, stream>>>(dflag);
    detect_kernel<<<(ROWS + 255) / 256, 256, 0, stream>>>(
        (const unsigned char*)slide, (const unsigned char*)hinge,
        (const unsigned char*)glob, m_idx, dflag);

    // weights -> bf16 transposed (every call: ws is re-poisoned)
    wconv_t<<<(L_ * H_ * 768 + 255) / 256, 256, 0, stream>>>(Wqkv, WqkvT, H_, 768, L_ * H_ * 768);
    wconv_t<<<(L_ * H_ * H_  + 255) / 256, 256, 0, stream>>>(Wo,   WoT,   H_, H_,  L_ * H_ * H_);
    wconv_t<<<(L_ * H_ * 1024+ 255) / 256, 256, 0, stream>>>(W1,   W1T,   H_, 1024,L_ * H_ * 1024);
    wconv_t<<<(L_ * 1024* H_ + 255) / 256, 256, 0, stream>>>(W2,   W2T,   1024, H_,L_ * 1024 * H_);

    embed_kernel<<<ROWS / 4, 256, 0, stream>>>(act, slide, hinge, glob, m_idx, dflag,
                                               Ws, bs, Wh, bh, Wg, Wact, pos, X);

    for (int l = 0; l < L_; ++l) {
        ln_kernel<true><<<ROWS / 4, 256, 0, stream>>>(X, ln1s + l * H_, ln1b + l * H_,
                                                      loraA + (size_t)l * M_ * H_ * RANK_, m_idx, Hbf, Rbuf);
        gemm_k<0><<<dim3(6, 384), 256, 0, stream>>>(Hbf, WqkvT + (size_t)l * H_ * 768,
                                                    bqkv + l * 768, Rbuf,
                                                    loraB + (size_t)l * M_ * RANK_ * 768, m_idx,
                                                    QKVG, nullptr, H_, 768);
        attn_kernel<<<NTOK * HEADS_, 64, 0, stream>>>(QKVG, m_idx, Obf);
        gemm_k<2><<<dim3(2, 384), 256, 0, stream>>>(Obf, WoT + (size_t)l * H_ * H_,
                                                    bo + l * H_, g1 + l * H_, nullptr, nullptr,
                                                    nullptr, X, H_, H_);
        ln_kernel<false><<<ROWS / 4, 256, 0, stream>>>(X, ln2s + l * H_, ln2b + l * H_,
                                                       nullptr, nullptr, Hbf, nullptr);
        gemm_k<1><<<dim3(8, 384), 256, 0, stream>>>(Hbf, W1T + (size_t)l * H_ * 1024,
                                                    b1 + l * 1024, nullptr, nullptr, nullptr,
                                                    QKVG, nullptr, H_, 1024);
        gemm_k<2><<<dim3(2, 384), 256, 0, stream>>>(QKVG, W2T + (size_t)l * 1024 * H_,
                                                    b2 + l * H_, g2 + l * H_, nullptr, nullptr,
                                                    nullptr, X, 1024, H_);
    }

    lnf_kernel<<<ROWS / 4, 256, 0, stream>>>(X, lnfs, lnfb);
}

// Round 3
// 1444.536 us; speedup vs baseline: 1.1233x; 1.1233x over previous
//
#include <hip/hip_runtime.h>
#include <cstdint>
#include <cstddef>

#define B_     16
#define T_     128
#define J_     24
#define H_     256
#define HEADS_ 8
#define DH_    32
#define L_     4
#define RANK_  8
#define M_     12
#define NTOK   (B_*T_)       // 2048
#define ROWS   (NTOK*J_)     // 49152
#define HAS_G_MASK 3821      // bit m set iff NUM_GLOBAL_LIST[m] > 0

typedef __attribute__((ext_vector_type(8))) short short8;
typedef __attribute__((ext_vector_type(4))) float f32x4;

__constant__ int cNJ[M_] = {8, 10, 12, 14, 16, 18, 20, 22, 24, 9, 13, 17};

__device__ __forceinline__ float bf2f(unsigned short u) {
    union { unsigned int i; float f; } c; c.i = ((unsigned int)u) << 16; return c.f;
}
__device__ __forceinline__ unsigned short f2bf(float f) {
    union { float f; unsigned int i; } c; c.f = f;
    unsigned int x = c.i;
    return (unsigned short)((x + 0x7fffu + ((x >> 16) & 1u)) >> 16);
}
__device__ __forceinline__ float asf(unsigned int u) {
    union { unsigned int i; float f; } c; c.i = u; return c.f;
}
__device__ __forceinline__ void gload16(const void* g, void* l) {
    __builtin_amdgcn_global_load_lds((const __attribute__((address_space(1))) void*)g,
                                     (__attribute__((address_space(3))) void*)l, 16, 0, 0);
}

// ---------------------------------------------------------------- mask dtype probe
__global__ void zero_flag(int* f) { *f = 0; }

__global__ __launch_bounds__(256) void detect_kernel(
    const unsigned char* __restrict__ sl, const unsigned char* __restrict__ hi,
    const unsigned char* __restrict__ gl, const int* __restrict__ m_idx,
    int* __restrict__ flag) {
    int rj = blockIdx.x * 256 + threadIdx.x;
    if (rj >= ROWS) return;
    int b = rj / (T_ * J_);
    int j = rj % J_;
    int valid = (j < cNJ[m_idx[b]]) ? 1 : 0;
    int cnt = (sl[rj] != 0) + (hi[rj] != 0) + (gl[rj] != 0);
    if (cnt != valid) atomicOr(flag, 1);
}

// ---------------------------------------------------------------- weights f32 -> bf16 transposed
__global__ void wconv_t(const float* __restrict__ W, unsigned short* __restrict__ WT,
                        int K, int Nc, int total) {
    int i = blockIdx.x * 256 + threadIdx.x;
    if (i >= total) return;
    int kn = K * Nc;
    int l = i / kn;
    int r = i - l * kn;
    int k = r / Nc;
    int n = r - k * Nc;
    WT[(size_t)l * kn + (size_t)n * K + k] = f2bf(W[i]);
}

// ---------------------------------------------------------------- embedding (wave per row)
__global__ __launch_bounds__(256) void embed_kernel(
    const float* __restrict__ act, const void* __restrict__ slide,
    const void* __restrict__ hinge, const void* __restrict__ glob,
    const int* __restrict__ m_idx, const int* __restrict__ flag,
    const float* __restrict__ Ws, const float* __restrict__ bs,
    const float* __restrict__ Wh, const float* __restrict__ bh,
    const float* __restrict__ Wg, const float* __restrict__ Wact,
    const float* __restrict__ pos, float* __restrict__ X) {
    int rj = (blockIdx.x << 2) + (threadIdx.x >> 6);
    int lane = threadIdx.x & 63;
    int b = rj / (T_ * J_);
    int j = rj % J_;
    int m = m_idx[b];
    bool valid = j < cNJ[m];
    bool s, hh, gl;
    if (*flag) {
        s  = ((const int*)slide)[rj] != 0;
        hh = ((const int*)hinge)[rj] != 0;
        gl = ((const int*)glob)[rj]  != 0;
    } else {
        s  = ((const unsigned char*)slide)[rj] != 0;
        hh = ((const unsigned char*)hinge)[rj] != 0;
        gl = ((const unsigned char*)glob)[rj]  != 0;
    }
    float a1 = act[rj];
    int h0 = lane << 2;
    float e0 = 0.f, e1 = 0.f, e2 = 0.f, e3 = 0.f;
    if (s) {
        float4 w = *(const float4*)(Ws + h0); float4 bb = *(const float4*)(bs + h0);
        e0 = a1 * w.x + bb.x; e1 = a1 * w.y + bb.y; e2 = a1 * w.z + bb.z; e3 = a1 * w.w + bb.w;
    } else if (hh) {
        float4 w = *(const float4*)(Wh + h0); float4 bb = *(const float4*)(bh + h0);
        e0 = a1 * w.x + bb.x; e1 = a1 * w.y + bb.y; e2 = a1 * w.z + bb.z; e3 = a1 * w.w + bb.w;
    } else if (gl && ((HAS_G_MASK >> m) & 1)) {
        float4 w = *(const float4*)(Wg + m * H_ + h0);
        e0 = a1 * w.x; e1 = a1 * w.y; e2 = a1 * w.z; e3 = a1 * w.w;
    }
    if (valid) {
        float4 wa = *(const float4*)(Wact + h0);
        e0 += wa.x; e1 += wa.y; e2 += wa.z; e3 += wa.w;
    }
    float4 pv = *(const float4*)(pos + (size_t)(m * J_ + j) * H_ + h0);
    float4 out; out.x = e0 + pv.x; out.y = e1 + pv.y; out.z = e2 + pv.z; out.w = e3 + pv.w;
    *(float4*)(X + ((size_t)rj << 8) + h0) = out;
}

// ---------------------------------------------------------------- LayerNorm (+ optional LoRA-A), wave per row
template<bool LORA>
__global__ __launch_bounds__(256) void ln_kernel(
    const float* __restrict__ X, const float* __restrict__ sc, const float* __restrict__ bi,
    const float* __restrict__ lA, const int* __restrict__ m_idx,
    unsigned short* __restrict__ Hbf, float* __restrict__ Rbuf) {
    int row = (blockIdx.x << 2) + (threadIdx.x >> 6);
    int lane = threadIdx.x & 63;
    int h0 = lane << 2;
    float4 xv = *(const float4*)(X + ((size_t)row << 8) + h0);
    float s1 = xv.x + xv.y + xv.z + xv.w;
    float s2 = xv.x * xv.x + xv.y * xv.y + xv.z * xv.z + xv.w * xv.w;
    #pragma unroll
    for (int o = 32; o; o >>= 1) { s1 += __shfl_xor(s1, o); s2 += __shfl_xor(s2, o); }
    float mu = s1 * (1.f / H_);
    float var = s2 * (1.f / H_) - mu * mu;
    float rs = rsqrtf(var + 1e-5f);
    float4 scv = *(const float4*)(sc + h0);
    float4 biv = *(const float4*)(bi + h0);
    float hn0 = (xv.x - mu) * rs * scv.x + biv.x;
    float hn1 = (xv.y - mu) * rs * scv.y + biv.y;
    float hn2 = (xv.z - mu) * rs * scv.z + biv.z;
    float hn3 = (xv.w - mu) * rs * scv.w + biv.w;
    ushort4 o4; o4.x = f2bf(hn0); o4.y = f2bf(hn1); o4.z = f2bf(hn2); o4.w = f2bf(hn3);
    *(ushort4*)(Hbf + ((size_t)row << 8) + h0) = o4;
    if (LORA) {
        int t = m_idx[row / (J_ * T_)];
        const float* Ap = lA + (size_t)t * (H_ * RANK_) + h0 * RANK_;
        float4 av[8];
        #pragma unroll
        for (int c = 0; c < 8; ++c) av[c] = ((const float4*)Ap)[c];
        float hn[4] = {hn0, hn1, hn2, hn3};
        float p[RANK_];
        #pragma unroll
        for (int k = 0; k < RANK_; ++k) p[k] = 0.f;
        #pragma unroll
        for (int i = 0; i < 4; ++i)
            #pragma unroll
            for (int k = 0; k < RANK_; ++k) {
                int idx = i * RANK_ + k;
                float a = (idx & 3) == 0 ? av[idx >> 2].x : (idx & 3) == 1 ? av[idx >> 2].y
                        : (idx & 3) == 2 ? av[idx >> 2].z : av[idx >> 2].w;
                p[k] += hn[i] * a;
            }
        #pragma unroll
        for (int k = 0; k < RANK_; ++k)
            #pragma unroll
            for (int o = 32; o; o >>= 1) p[k] += __shfl_xor(p[k], o);
        if (lane == 0) {
            #pragma unroll
            for (int k = 0; k < RANK_; ++k) Rbuf[(size_t)row * RANK_ + k] = p[k];
        }
    }
}

// ---------------------------------------------------------------- final LayerNorm (in place, wave per row)
__global__ __launch_bounds__(256) void lnf_kernel(
    float* __restrict__ X, const float* __restrict__ sc, const float* __restrict__ bi) {
    int row = (blockIdx.x << 2) + (threadIdx.x >> 6);
    int lane = threadIdx.x & 63;
    int h0 = lane << 2;
    float4 xv = *(const float4*)(X + ((size_t)row << 8) + h0);
    float s1 = xv.x + xv.y + xv.z + xv.w;
    float s2 = xv.x * xv.x + xv.y * xv.y + xv.z * xv.z + xv.w * xv.w;
    #pragma unroll
    for (int o = 32; o; o >>= 1) { s1 += __shfl_xor(s1, o); s2 += __shfl_xor(s2, o); }
    float mu = s1 * (1.f / H_);
    float var = s2 * (1.f / H_) - mu * mu;
    float rs = rsqrtf(var + 1e-5f);
    float4 scv = *(const float4*)(sc + h0);
    float4 biv = *(const float4*)(bi + h0);
    float4 out;
    out.x = (xv.x - mu) * rs * scv.x + biv.x;
    out.y = (xv.y - mu) * rs * scv.y + biv.y;
    out.z = (xv.z - mu) * rs * scv.z + biv.z;
    out.w = (xv.w - mu) * rs * scv.w + biv.w;
    *(float4*)(X + ((size_t)row << 8) + h0) = out;
}

// ---------------------------------------------------------------- GEMM: C = A[ROWSxK] @ B[KxNc] (+epilogue)
template<int EPI>
__global__ __launch_bounds__(256) void gemm_k(
    const unsigned short* __restrict__ A, const unsigned short* __restrict__ BT,
    const float* __restrict__ bias,
    const float* __restrict__ aux1,   // QKV: Rbuf   RESID: gvec
    const float* __restrict__ aux2,   // QKV: loraB_l [M][RANK][768]
    const int* __restrict__ m_idx,
    unsigned short* __restrict__ outB, float* __restrict__ outF,
    int K, int Nc) {
    __shared__ __align__(16) unsigned short As[128 * 64];
    __shared__ __align__(16) unsigned short Bs[128 * 64];
    int gx = gridDim.x;
    int nwg = gx * gridDim.y;
    int id = blockIdx.y * gx + blockIdx.x;
    int bx = blockIdx.x, by = blockIdx.y;
    if ((nwg & 7) == 0) {
        int q8 = nwg >> 3;
        int sid = (id & 7) * q8 + (id >> 3);
        bx = sid % gx; by = sid / gx;
    }
    int col0 = bx * 128;
    int row0 = by * 128;
    int tid = threadIdx.x;
    int wv = tid >> 6, lane = tid & 63;
    int wm = wv >> 1, wn = wv & 1;

    f32x4 acc[4][4];
    const f32x4 z = {0.f, 0.f, 0.f, 0.f};
    #pragma unroll
    for (int mi = 0; mi < 4; ++mi)
        #pragma unroll
        for (int ni = 0; ni < 4; ++ni) acc[mi][ni] = z;

    for (int k0 = 0; k0 < K; k0 += 64) {
        #pragma unroll
        for (int it = 0; it < 4; ++it) {
            int f = (tid << 4) + (it << 12);
            int r = f >> 7;
            int ce = (f & 127) >> 1;
            gload16(A  + (size_t)(row0 + r) * K + k0 + ce, (char*)As + f);
            gload16(BT + (size_t)(col0 + r) * K + k0 + ce, (char*)Bs + f);
        }
        __syncthreads();
        #pragma unroll
        for (int kk = 0; kk < 64; kk += 32) {
            short8 af[4], bfr[4];
            int ko = kk + ((lane >> 4) << 3);
            #pragma unroll
            for (int q = 0; q < 4; ++q) {
                af[q]  = *(const short8*)(As + ((wm * 64 + q * 16 + (lane & 15)) << 6) + ko);
                bfr[q] = *(const short8*)(Bs + ((wn * 64 + q * 16 + (lane & 15)) << 6) + ko);
            }
            #pragma unroll
            for (int mi = 0; mi < 4; ++mi)
                #pragma unroll
                for (int ni = 0; ni < 4; ++ni)
                    acc[mi][ni] = __builtin_amdgcn_mfma_f32_16x16x32_bf16(af[mi], bfr[ni], acc[mi][ni], 0, 0, 0);
        }
        __syncthreads();
    }

    int rbase = row0 + wm * 64 + ((lane >> 4) << 2);
    int cbase = col0 + wn * 64 + (lane & 15);

    if (EPI == 0) {
        int t = m_idx[row0 / (J_ * T_)];
        const float* lB = aux2 + (size_t)t * (RANK_ * 3 * H_);
        float lbv[4][RANK_];
        #pragma unroll
        for (int ni = 0; ni < 4; ++ni)
            #pragma unroll
            for (int kq = 0; kq < RANK_; ++kq)
                lbv[ni][kq] = lB[kq * (3 * H_) + cbase + ni * 16];
        #pragma unroll
        for (int mi = 0; mi < 4; ++mi) {
            #pragma unroll
            for (int r = 0; r < 4; ++r) {
                int row = rbase + mi * 16 + r;
                const float* Rr = aux1 + (size_t)row * RANK_;
                float rv[RANK_];
                #pragma unroll
                for (int kq = 0; kq < RANK_; ++kq) rv[kq] = Rr[kq];
                #pragma unroll
                for (int ni = 0; ni < 4; ++ni) {
                    int col = cbase + ni * 16;
                    float val = acc[mi][ni][r] + bias[col];
                    #pragma unroll
                    for (int kq = 0; kq < RANK_; ++kq) val += rv[kq] * lbv[ni][kq];
                    outB[(size_t)row * (3 * H_) + col] = f2bf(val);
                }
            }
        }
    } else if (EPI == 1) {
        #pragma unroll
        for (int mi = 0; mi < 4; ++mi)
            #pragma unroll
            for (int r = 0; r < 4; ++r) {
                int row = rbase + mi * 16 + r;
                #pragma unroll
                for (int ni = 0; ni < 4; ++ni) {
                    int col = cbase + ni * 16;
                    float u = acc[mi][ni][r] + bias[col];
                    float zz = 0.7978845608028654f * (u + 0.044715f * u * u * u);
                    float tt = __expf(-2.f * fabsf(zz));
                    float th = (1.f - tt) / (1.f + tt);
                    th = zz < 0.f ? -th : th;
                    outB[(size_t)row * Nc + col] = f2bf(0.5f * u * (1.f + th));
                }
            }
    } else {
        #pragma unroll
        for (int mi = 0; mi < 4; ++mi)
            #pragma unroll
            for (int r = 0; r < 4; ++r) {
                int row = rbase + mi * 16 + r;
                #pragma unroll
                for (int ni = 0; ni < 4; ++ni) {
                    int col = cbase + ni * 16;
                    float u = acc[mi][ni][r] + bias[col];
                    outF[(size_t)row * H_ + col] += aux1[col] * u;
                }
            }
    }
}

// ---------------------------------------------------------------- attention v2
// 256 threads = 4 waves; wave w handles head (blk&1)*4+w of token n = blk>>1.
// Per-wave LDS (bf16 pairs packed in u32, all accesses conflict-free):
//   q2[24][18]  row-major d-pairs      k2[16][26]  d-pair-major (transposed)
//   v2[24][18]  row-major d-pairs      sc[24][27]  probabilities (odd pad)
// No __syncthreads anywhere: each wave owns its LDS slice.
__global__ __launch_bounds__(256) void attn_kernel(
    const unsigned short* __restrict__ QKV, const int* __restrict__ m_idx,
    unsigned short* __restrict__ O) {
    __shared__ unsigned int q2s[4][24][18];
    __shared__ unsigned int k2s[4][16][26];
    __shared__ unsigned int v2s[4][24][18];
    __shared__ float       scs[4][24][27];
    int w = threadIdx.x >> 6, lane = threadIdx.x & 63;
    int n = blockIdx.x >> 1;
    int hd = ((blockIdx.x & 1) << 2) + w;
    int nj = cNJ[m_idx[n >> 7]];
    unsigned int (*q2)[18] = q2s[w];
    unsigned int (*k2)[26] = k2s[w];
    unsigned int (*v2)[18] = v2s[w];
    float (*sc)[27] = scs[w];

    const unsigned short* base = QKV + (size_t)n * (J_ * 768) + hd * DH_;

    // ---- staging: 24 rows x 8 ushort4 per matrix (mat uniform per iteration)
    #pragma unroll
    for (int it = 0; it < 3; ++it) {
        int r = it * 64 + lane;
        int j = r >> 3, d0 = (r & 7) << 2, d2 = d0 >> 1;
        ushort4 x = *(const ushort4*)(base + (size_t)j * 768 + d0);
        q2[j][d2]     = (unsigned int)x.x | ((unsigned int)x.y << 16);
        q2[j][d2 + 1] = (unsigned int)x.z | ((unsigned int)x.w << 16);
    }
    #pragma unroll
    for (int it = 0; it < 3; ++it) {
        int r = it * 64 + lane;
        int j = r >> 3, d0 = (r & 7) << 2, d2 = d0 >> 1;
        ushort4 x = *(const ushort4*)(base + (size_t)j * 768 + 256 + d0);
        k2[d2][j]     = (unsigned int)x.x | ((unsigned int)x.y << 16);
        k2[d2 + 1][j] = (unsigned int)x.z | ((unsigned int)x.w << 16);
    }
    #pragma unroll
    for (int it = 0; it < 3; ++it) {
        int r = it * 64 + lane;
        int j = r >> 3, d0 = (r & 7) << 2, d2 = d0 >> 1;
        ushort4 x = *(const ushort4*)(base + (size_t)j * 768 + 512 + d0);
        v2[j][d2]     = (unsigned int)x.x | ((unsigned int)x.y << 16);
        v2[j][d2 + 1] = (unsigned int)x.z | ((unsigned int)x.w << 16);
    }

    // ---- QK^T + softmax, fused in registers (lanes 0-47: i=lane>>1, half rows)
    int i = lane >> 1, half = lane & 1;
    if (lane < 48) {
        float qf[32];
        #pragma unroll
        for (int d2 = 0; d2 < 16; ++d2) {
            unsigned int x = q2[i][d2];
            qf[2 * d2]     = asf(x << 16);
            qf[2 * d2 + 1] = asf(x & 0xffff0000u);
        }
        int jb = half * 12;
        float s[12];
        #pragma unroll
        for (int jj = 0; jj < 12; ++jj) {
            int j = jb + jj;
            float acc = 0.f;
            #pragma unroll
            for (int d2 = 0; d2 < 16; ++d2) {
                unsigned int x = k2[d2][j];
                acc += qf[2 * d2] * asf(x << 16);
                acc += qf[2 * d2 + 1] * asf(x & 0xffff0000u);
            }
            bool ok = (i < nj && j < nj) || (i == j);
            s[jj] = ok ? acc * 0.17677669529663687f : -1e30f;
        }
        float mx = s[0];
        #pragma unroll
        for (int jj = 1; jj < 12; ++jj) mx = fmaxf(mx, s[jj]);
        mx = fmaxf(mx, __shfl_xor(mx, 1));
        float sm = 0.f;
        #pragma unroll
        for (int jj = 0; jj < 12; ++jj) { float e = __expf(s[jj] - mx); s[jj] = e; sm += e; }
        sm += __shfl_xor(sm, 1);
        float inv = 1.f / sm;
        #pragma unroll
        for (int jj = 0; jj < 12; ++jj) sc[i][jb + jj] = s[jj] * inv;
    }

    // ---- PV: 16-lane groups share a row (sc reads broadcast), d2 per-lane
    #pragma unroll
    for (int it = 0; it < 6; ++it) {
        int i2 = it * 4 + (lane >> 4), d2 = lane & 15;
        float olo = 0.f, ohi = 0.f;
        #pragma unroll
        for (int j = 0; j < J_; ++j) {
            float p = sc[i2][j];
            unsigned int x = v2[j][d2];
            olo += p * asf(x << 16);
            ohi += p * asf(x & 0xffff0000u);
        }
        unsigned int o = (unsigned int)f2bf(olo) | ((unsigned int)f2bf(ohi) << 16);
        *(unsigned int*)(O + (size_t)(n * J_ + i2) * H_ + hd * DH_ + 2 * d2) = o;
    }
}

// ---------------------------------------------------------------- host
extern "C" void kernel_launch(void* const* d_in, const int* in_sizes, int n_in,
                              void* d_out, int out_size, void* d_ws, size_t ws_size,
                              hipStream_t stream) {
    (void)in_sizes; (void)n_in; (void)out_size; (void)ws_size;
    const float* act   = (const float*)d_in[0];
    const void*  slide = d_in[1];
    const void*  hinge = d_in[2];
    const void*  glob  = d_in[3];
    const int* m_idx  = (const int*)d_in[6];
    const float* Ws   = (const float*)d_in[7];
    const float* bs   = (const float*)d_in[8];
    const float* Wh   = (const float*)d_in[9];
    const float* bh   = (const float*)d_in[10];
    const float* Wg   = (const float*)d_in[11];
    const float* Wact = (const float*)d_in[12];
    const float* pos  = (const float*)d_in[13];
    const float* ln1s = (const float*)d_in[14];
    const float* ln1b = (const float*)d_in[15];
    const float* Wqkv = (const float*)d_in[16];
    const float* bqkv = (const float*)d_in[17];
    const float* loraA= (const float*)d_in[18];
    const float* loraB= (const float*)d_in[19];
    const float* Wo   = (const float*)d_in[20];
    const float* bo   = (const float*)d_in[21];
    const float* ln2s = (const float*)d_in[22];
    const float* ln2b = (const float*)d_in[23];
    const float* W1   = (const float*)d_in[24];
    const float* b1   = (const float*)d_in[25];
    const float* W2   = (const float*)d_in[26];
    const float* b2   = (const float*)d_in[27];
    const float* g1   = (const float*)d_in[28];
    const float* g2   = (const float*)d_in[29];
    const float* lnfs = (const float*)d_in[30];
    const float* lnfb = (const float*)d_in[31];

    float* X = (float*)d_out;

    size_t off = 0;
    char* ws = (char*)d_ws;
    auto nxt = [&](size_t bytes) -> char* {
        char* p = ws + off; off += (bytes + 255) & ~(size_t)255; return p;
    };
    int*            dflag = (int*)nxt(256);
    unsigned short* Hbf   = (unsigned short*)nxt((size_t)ROWS * H_ * 2);
    unsigned short* QKVG  = (unsigned short*)nxt((size_t)ROWS * 1024 * 2);
    float*          Rbuf  = (float*)nxt((size_t)ROWS * RANK_ * 4);
    unsigned short* WqkvT = (unsigned short*)nxt((size_t)L_ * H_ * 768 * 2);
    unsigned short* WoT   = (unsigned short*)nxt((size_t)L_ * H_ * H_ * 2);
    unsigned short* W1T   = (unsigned short*)nxt((size_t)L_ * H_ * 1024 * 2);
    unsigned short* W2T   = (unsigned short*)nxt((size_t)L_ * 1024 * H_ * 2);
    unsigned short* Obf   = Hbf;

    zero_flag<<<1, 1, 0, stream>>>(dflag);
    detect_kernel<<<(ROWS + 255) / 256, 256, 0, stream>>>(
        (const unsigned char*)slide, (const unsigned char*)hinge,
        (const unsigned char*)glob, m_idx, dflag);

    wconv_t<<<(L_ * H_ * 768 + 255) / 256, 256, 0, stream>>>(Wqkv, WqkvT, H_, 768, L_ * H_ * 768);
    wconv_t<<<(L_ * H_ * H_  + 255) / 256, 256, 0, stream>>>(Wo,   WoT,   H_, H_,  L_ * H_ * H_);
    wconv_t<<<(L_ * H_ * 1024+ 255) / 256, 256, 0, stream>>>(W1,   W1T,   H_, 1024,L_ * H_ * 1024);
    wconv_t<<<(L_ * 1024* H_ + 255) / 256, 256, 0, stream>>>(W2,   W2T,   1024, H_,L_ * 1024 * H_);

    embed_kernel<<<ROWS / 4, 256, 0, stream>>>(act, slide, hinge, glob, m_idx, dflag,
                                               Ws, bs, Wh, bh, Wg, Wact, pos, X);

    for (int l = 0; l < L_; ++l) {
        ln_kernel<true><<<ROWS / 4, 256, 0, stream>>>(X, ln1s + l * H_, ln1b + l * H_,
                                                      loraA + (size_t)l * M_ * H_ * RANK_, m_idx, Hbf, Rbuf);
        gemm_k<0><<<dim3(6, 384), 256, 0, stream>>>(Hbf, WqkvT + (size_t)l * H_ * 768,
                                                    bqkv + l * 768, Rbuf,
                                                    loraB + (size_t)l * M_ * RANK_ * 768, m_idx,
                                                    QKVG, nullptr, H_, 768);
        attn_kernel<<<NTOK * 2, 256, 0, stream>>>(QKVG, m_idx, Obf);
        gemm_k<2><<<dim3(2, 384), 256, 0, stream>>>(Obf, WoT + (size_t)l * H_ * H_,
                                                    bo + l * H_, g1 + l * H_, nullptr, nullptr,
                                                    nullptr, X, H_, H_);
        ln_kernel<false><<<ROWS / 4, 256, 0, stream>>>(X, ln2s + l * H_, ln2b + l * H_,
                                                       nullptr, nullptr, Hbf, nullptr);
        gemm_k<1><<<dim3(8, 384), 256, 0, stream>>>(Hbf, W1T + (size_t)l * H_ * 1024,
                                                    b1 + l * 1024, nullptr, nullptr, nullptr,
                                                    QKVG, nullptr, H_, 1024);
        gemm_k<2><<<dim3(2, 384), 256, 0, stream>>>(QKVG, W2T + (size_t)l * 1024 * H_,
                                                    b2 + l * H_, g2 + l * H_, nullptr, nullptr,
                                                    nullptr, X, 1024, H_);
    }

    lnf_kernel<<<ROWS / 4, 256, 0, stream>>>(X, lnfs, lnfb);
}